// Round 19
// baseline (50.741 us; speedup 1.0000x reference)
//
#include <hip/hip_runtime.h>
#include <stdint.h>

#define INPUT_SCALE 0.0078125f   // 2^-7

typedef uint32_t u32x4 __attribute__((ext_vector_type(4)));
typedef uint32_t u32x4b __attribute__((ext_vector_type(4), aligned(4)));

__device__ __forceinline__ u32x4 mqsad(uint64_t s0, uint32_t ref, u32x4 acc) {
#if __has_builtin(__builtin_amdgcn_mqsad_u32_u8)
    return __builtin_amdgcn_mqsad_u32_u8(s0, ref, acc);
#else
    u32x4 d;
    asm("v_mqsad_u32_u8 %0, %1, %2, %3" : "=&v"(d) : "v"(s0), "v"(ref), "v"(acc));
    return d;
#endif
}

__device__ __forceinline__ uint32_t alignb(uint32_t hi, uint32_t lo, int b) {
    return __builtin_amdgcn_alignbyte(hi, lo, b);
}

__device__ __forceinline__ uint32_t qbyte(float x) {
    // round(clip(x*128, -127, 127)) + 128  (rintf = round-half-even, matches jnp.round)
    float v = fminf(fmaxf(x * 128.0f, -127.0f), 127.0f);
    return (uint32_t)((int)rintf(v) + 128);
}

// Planar padded geometry (R13, HW-verified): plane = (n*32+c), row 136 B =
// [4 pad][128][4 pad], 130 rows. All pad bytes 0x80 (quantized zero).
#define ROWB 136
#define PLANEB (130 * ROWB)       // 17680 B
#define ROWU 34
#define PLANEU (130 * ROWU)       // 4420 u32

// ---------------- Kernel A: weight scale + mqsad ref pack (3 blocks) ----------------
// wref[(kh*32 + c)*32 + f] = bytes(qw0+128, qw1+128, qw2+128, 0); byte3==0 is
// MASKED by mqsad (weight bytes are never 0 since qw+128 >= 1). Each block
// redundantly max-reduces (deterministic) and packs its own kh slice.
__global__ __launch_bounds__(512) void quant_weight(const float* __restrict__ w,
                                                    uint32_t* __restrict__ qwp) {
    __shared__ float red[512];
    __shared__ float s_inv;
    int tid = threadIdx.x;
    float m = 0.0f;
    for (int i = tid; i < 9216; i += 512) m = fmaxf(m, fabsf(w[i]));
    red[tid] = m;
    __syncthreads();
    for (int s = 256; s > 0; s >>= 1) {
        if (tid < s) red[tid] = fmaxf(red[tid], red[tid + s]);
        __syncthreads();
    }
    if (tid == 0) {
        float s = fmaxf(red[0] / 127.0f, 1e-8f);
        int e; float fr = frexpf(s, &e);            // s = fr * 2^e, fr in [0.5,1)
        int k = (fr >= 0.70710678118654752f) ? e : e - 1;  // round(log2(s))
        s_inv = exp2f((float)(-k));                 // 1/s_w, exact power of 2
    }
    __syncthreads();
    float inv = s_inv;
    int kh = blockIdx.x;                            // 3 blocks
    for (int u = tid; u < 1024; u += 512) {
        int c = u >> 5, f = u & 31;
        uint32_t pk = 0;
        #pragma unroll
        for (int kw = 0; kw < 3; ++kw) {
            float v = w[((f * 32 + c) * 3 + kh) * 3 + kw] * inv;
            v = fminf(fmaxf(v, -127.0f), 127.0f);
            pk |= ((uint32_t)((int)rintf(v) + 128) & 0xFFu) << (8 * kw);
        }
        qwp[(kh * 32 + c) * 32 + f] = pk;           // byte 3 stays 0 -> masked
    }
}

// ---------------- Kernel B: quantize + pack x to planar padded bytes (R13) ----------
__global__ __launch_bounds__(512) void quant_pack_x(const float4* __restrict__ x4,
                                                    uint32_t* __restrict__ qxp) {
    int b = blockIdx.x;
    int tid = threadIdx.x;
    if (b < 4096) {
        int t = b * 512 + tid;            // [n:4][c:5][h:7][wq:5]
        int wq = t & 31;
        int h = (t >> 5) & 127;
        int c = (t >> 12) & 31;
        int n = t >> 17;
        float4 v = x4[(((size_t)(n * 32 + c) * 128) + h) * 32 + wq];
        uint32_t pk = qbyte(v.x) | (qbyte(v.y) << 8) | (qbyte(v.z) << 16) | (qbyte(v.w) << 24);
        qxp[(size_t)(n * 32 + c) * PLANEU + (h + 1) * ROWU + 1 + wq] = pk;
    } else {
        int idx = (b - 4096) * 512 + tid;  // 324 border u32 per plane x 512 planes
        int p = idx / 324, k = idx - p * 324;
        int r, cu;
        if (k < 34)       { r = 0;   cu = k; }
        else if (k < 68)  { r = 129; cu = k - 34; }
        else { int j = k - 68; r = 1 + (j >> 1); cu = (j & 1) ? 33 : 0; }
        qxp[(size_t)p * PLANEU + r * ROWU + cu] = 0x80808080u;
    }
}

// ---------------- Kernel C: MQSAD conv at 4 waves/SIMD ----------------
// 512 blocks x 512 thr = 2 blocks/CU x 8 waves = 16 waves/CU. Thread: 4
// consecutive outputs (quad q) of row h x 8 filters (fg). Per (kh,c): one 16 B
// global load (L2-hit, vmcnt) + one uniform s_load_dwordx8 (lgkm = weights
// only) + 2 alignbyte + 8 mqsad (128 cy busy). R13 proved this inner loop at
// ~1-2 waves/SIMD -> 48% duty; this round supplies the missing TLP.
__global__ __launch_bounds__(512, 4) void adder_conv(const uint32_t* __restrict__ qxp,
                                                     const uint32_t* __restrict__ qwp,
                                                     float* __restrict__ out) {
    int tid = threadIdx.x;
    // XCD swizzle: 512 blocks, XCD k gets 64 consecutive work ids (2 images).
    int b = ((blockIdx.x & 7) << 6) | (blockIdx.x >> 3);
    int n = b >> 5;                       // image
    int rb = b & 31;                      // row-block of 4
    int fg = __builtin_amdgcn_readfirstlane(tid >> 7);  // filter group (wave-uniform)
    int hl = (tid >> 5) & 3;
    int q = tid & 31;                     // output quad: cols 4q .. 4q+3
    int h = rb * 4 + hl;

    // 16 B load at byte 4q of buffer row (h+kh) covers input cols 4q-1 .. 4q+11;
    // windows need bytes 4q+3 .. 4q+9 (left pad = 4 B).
    const char* base0 = (const char*)qxp + (size_t)(n * 32) * PLANEB + (size_t)h * ROWB + 4 * q;

    u32x4 acc[8];
    #pragma unroll
    for (int f = 0; f < 8; ++f) acc[f] = (u32x4)0;

    #pragma unroll 1
    for (int kh = 0; kh < 3; ++kh) {
        #pragma unroll 4
        for (int c = 0; c < 32; ++c) {
            u32x4 d = *(const u32x4b*)(base0 + (size_t)c * PLANEB + kh * ROWB);
            uint32_t b0 = alignb(d.y, d.x, 3);    // bytes 3..6
            uint32_t b1 = alignb(d.z, d.y, 3);    // bytes 7..10
            uint64_t s0 = ((uint64_t)b1 << 32) | b0;   // windows for outputs 4q..4q+3
            const uint32_t* wt = qwp + (kh * 32 + c) * 32 + fg * 8;  // uniform -> s_load_dwordx8
            #pragma unroll
            for (int f = 0; f < 8; ++f) {
                acc[f] = mqsad(s0, wt[f], acc[f]);
            }
        }
    }

    size_t obase = (((size_t)n * 32 + fg * 8) * 16384) + (size_t)h * 128 + 4 * q;
    #pragma unroll
    for (int f = 0; f < 8; ++f) {
        float4 o = make_float4(-(float)acc[f].x * INPUT_SCALE,
                               -(float)acc[f].y * INPUT_SCALE,
                               -(float)acc[f].z * INPUT_SCALE,
                               -(float)acc[f].w * INPUT_SCALE);
        *(float4*)(out + obase + (size_t)f * 16384) = o;
    }
}

extern "C" void kernel_launch(void* const* d_in, const int* in_sizes, int n_in,
                              void* d_out, int out_size, void* d_ws, size_t ws_size,
                              hipStream_t stream) {
    const float* x = (const float*)d_in[0];       // (16,32,128,128)
    const float* w = (const float*)d_in[1];       // (32,32,3,3)
    float* out = (float*)d_out;                   // (16,32,128,128)

    uint32_t* qwp = (uint32_t*)d_ws;                          // 12288 B
    uint32_t* qxp = (uint32_t*)((char*)d_ws + 16384);         // 512 * 17680 B = 9.05 MB

    quant_weight<<<3, 512, 0, stream>>>(w, qwp);
    quant_pack_x<<<4420, 512, 0, stream>>>((const float4*)x, qxp);
    adder_conv<<<512, 512, 0, stream>>>(qxp, qwp, out);
}